// Round 13
// baseline (92.217 us; speedup 1.0000x reference)
//
#include <hip/hip_runtime.h>

// Batched 10-qubit statevector simulator — one 64-lane wave per sample.
// State: 1024 complex amps; s = (r<<6)|lane; qubit q <-> bit (9-q):
//   qubits 0..3 -> register-index bits (16 complex float2 per lane)
//   qubits 4..9 -> lane bits (butterfly exchanges)
// Per layer per qubit, RY(a)RZ(b)RZ(g)RY(d) fuse into one SU(2)
// U = [[u, -conj(v)],[v, conj(u)]], p=(b+g)/2.
// R1-R10 (kept): lane-parallel coefficient precompute + readlane broadcast;
//   float2 state -> v_pk_fma; masks 1,2,8 via DPP, mask 4 via 2-DPP chain;
//   layer-0 product-state construction; ring-4 folded into epilogue parities.
// R11: order staggering was NEUTRAL -> aggregate DS throughput (not phase
//   sync) is the co-limiter: 392 DS/wave x 16 waves x ~6cyc == the 37%
//   non-VALU time.
// R12: RING FOLDING. CNOT(q,t)∘G_t == G_t with output row selected by
//   bit_t⊕bit_q instead of bit_t: (P,Q) per lane from {u,ū,v,-v̄} by (bt,bq).
//   Interleave: G0,G1,C01,G2,C12,G3,C23 (SWAPRs), then G4..G9 each carrying
//   its ring edge (C(3,4) ctrl=r-bit0 -> compile-time per-reg coeff set;
//   C(4,5)..C(8,9) ctrl=lane bit -> per-lane cndmask). C(9,0) stays as the
//   cndmask reg swap. Rings 1-3's 32-bperm chains DELETED: DS/wave 392->296.
//   Ring-0 stays explicit (layer 0 = construction, nothing to fold into).

constexpr int NQ  = 10;
constexpr int NL  = 5;
constexpr int OBS = 10;

typedef float f2 __attribute__((ext_vector_type(2)));

__device__ __forceinline__ float readlane_f(float v, int l) {
    return __int_as_float(__builtin_amdgcn_readlane(__float_as_int(v), l));
}
__device__ __forceinline__ float bperm_f(int byte_addr, float v) {
    return __int_as_float(__builtin_amdgcn_ds_bpermute(byte_addr, __float_as_int(v)));
}
template <int CTRL>
__device__ __forceinline__ float dpp_f(float v) {
    return __int_as_float(__builtin_amdgcn_update_dpp(
        0, __float_as_int(v), CTRL, 0xF, 0xF, true));
}
// xor-exchange across lanes; M compile-time -> branches fold.
__device__ __forceinline__ float xor_lane(float v, int M, int a16, int a32) {
    switch (M) {
    case 1:  return dpp_f<0xB1>(v);               // quad_perm [1,0,3,2]
    case 2:  return dpp_f<0x4E>(v);               // quad_perm [2,3,0,1]
    case 8:  return dpp_f<0x128>(v);              // row_ror:8 == lane^8
    case 4:  return dpp_f<0x141>(dpp_f<0x1B>(v)); // xor3 ∘ xor7 = xor4
    case 16: return bperm_f(a16, v);
    default: return bperm_f(a32, v);              // 32
    }
}

// register-bit gate (qubit Q in 0..3), standard (no fold)
template <int Q>
__device__ __forceinline__ void reg_gate(f2* c, float ur, float ui,
                                         float vr, float vi) {
    const f2 kUU  = {ur, ur};
    const f2 kUIm = {-ui, ui};
    const f2 kVVn = {-vr, -vr};
    const f2 kVV  = {vr, vr};
    const f2 kVIm = {-vi, vi};
    const f2 kUIp = {ui, -ui};
    constexpr int m = 1 << (3 - Q);
#pragma unroll
    for (int r0 = 0; r0 < 16; ++r0) {
        if (r0 & m) continue;
        const int r1 = r0 | m;
        const f2 c0 = c[r0], c1 = c[r1];
        const f2 c0s = c0.yx, c1s = c1.yx;
        c[r0] = kUU*c0 + kUIm*c0s + kVVn*c1 + kVIm*c1s;
        c[r1] = kVV*c0 + kVIm*c0s + kUU*c1  + kUIp*c1s;
    }
}

// lane-bit gate with optional folded ring edge.
// MT = target mask; BQMASK = ring-ctrl lane mask (0 = no fold);
// REGFOLD = ring ctrl is r-bit0 (C(3,4): per-reg compile-time fold).
// (P,Q) by (bt,bq): (0,0):(u,-v̄) (1,0):(ū,v) (0,1):(v,ū) (1,1):(-v̄,u)
template <int MT, int BQMASK, bool REGFOLD>
__device__ __forceinline__ void lane_gate(f2* c, int lane,
                                          float ur, float ui,
                                          float vr, float vi,
                                          int a16, int a32) {
    const bool bt = (lane & MT) != 0;
    if constexpr (REGFOLD) {
        // bq=0 set (even r) and bq=1 set (odd r)
        const float Pr0 = ur,              Pi0 = bt ? -ui : ui;
        const float Qr0 = bt ? vr : -vr,   Qi0 = vi;
        const float Pr1 = bt ? -vr : vr,   Pi1 = vi;
        const float Qr1 = ur,              Qi1 = bt ? ui : -ui;
        const f2 kP0 = {Pr0, Pr0}, kPs0 = {-Pi0, Pi0};
        const f2 kQ0 = {Qr0, Qr0}, kQs0 = {-Qi0, Qi0};
        const f2 kP1 = {Pr1, Pr1}, kPs1 = {-Pi1, Pi1};
        const f2 kQ1 = {Qr1, Qr1}, kQs1 = {-Qi1, Qi1};
#pragma unroll
        for (int r = 0; r < 16; ++r) {
            const f2 mv = c[r];
            f2 pv;
            pv.x = xor_lane(mv.x, MT, a16, a32);
            pv.y = xor_lane(mv.y, MT, a16, a32);
            if (r & 1) c[r] = kP1*mv + kPs1*mv.yx + kQ1*pv + kQs1*pv.yx;
            else       c[r] = kP0*mv + kPs0*mv.yx + kQ0*pv + kQs0*pv.yx;
        }
    } else {
        const bool bq = (BQMASK != 0) && ((lane & BQMASK) != 0);
        const float Pr = bq ? (bt ? -vr : vr) : ur;
        const float Pi = bq ? vi : (bt ? -ui : ui);
        const float Qr = bq ? ur : (bt ? vr : -vr);
        const float Qi = bq ? (bt ? ui : -ui) : vi;
        const f2 kP = {Pr, Pr}, kPs = {-Pi, Pi};
        const f2 kQ = {Qr, Qr}, kQs = {-Qi, Qi};
#pragma unroll
        for (int r = 0; r < 16; ++r) {
            const f2 mv = c[r];
            f2 pv;
            pv.x = xor_lane(mv.x, MT, a16, a32);
            pv.y = xor_lane(mv.y, MT, a16, a32);
            c[r] = kP*mv + kPs*mv.yx + kQ*pv + kQs*pv.yx;
        }
    }
}

__global__ __launch_bounds__(256, 4) void qsim_kernel(
    const float* __restrict__ x,       // (B, 10)
    const float* __restrict__ isc,     // (5, 20)
    const float* __restrict__ w,       // (5, 20)
    const float* __restrict__ oscale,  // (4)
    float* __restrict__ out,           // (B, 4)
    int B)
{
    const int lane = threadIdx.x & 63;
    const int wid  = (blockIdx.x * blockDim.x + threadIdx.x) >> 6;
    if (wid >= B) return;

    // ---- lane-parallel gate-coefficient computation (gates 0..49) ----
    float cUR, cUI, cVR, cVI;
    {
        const int g   = (lane < 50) ? lane : 49;
        const int q   = g % 10;
        const int lyr = g / 10;
        const float xq    = x[wid * OBS + q];
        const float alpha = isc[lyr * 2 * NQ + q]      * xq;
        const float beta  = isc[lyr * 2 * NQ + NQ + q] * xq;
        const float gamma = w[lyr * 2 * NQ + q];
        const float delta = w[lyr * 2 * NQ + NQ + q];
        float sa, ca, sp, cp, sd, cd;
        __sincosf(0.5f * alpha,          &sa, &ca);
        __sincosf(0.5f * (beta + gamma), &sp, &cp);
        __sincosf(0.5f * delta,          &sd, &cd);
        const float A = cd * ca, Bt = sd * sa;
        const float C = cd * sa, D  = sd * ca;
        cUR = (A - Bt) * cp;
        cUI = -(A + Bt) * sp;
        cVR = (C + D) * cp;
        cVI = (C - D) * sp;
    }

    // hoisted bpermute byte-addresses (loop-invariant)
    const int a16 = (lane ^ 16) * 4;
    const int a32 = (lane ^ 32) * 4;
    const int cnot_src  = (lane ^ (lane >> 1));
    const int addr_even = cnot_src * 4;            // r bit0 == 0
    const int addr_odd  = (cnot_src ^ 32) * 4;     // r bit0 == 1 (CNOT(3,4))

    f2 c[16];

    // ===== layer 0: direct product-state construction =====
    // amp(s) = prod_q (bit_q(s) ? v_q : u_q), gate column (u,v)=U|0>.
    {
        float Lr = 1.f, Li = 0.f;
#pragma unroll
        for (int q = 4; q < 10; ++q) {
            const float ur = readlane_f(cUR, q), ui = readlane_f(cUI, q);
            const float vr = readlane_f(cVR, q), vi = readlane_f(cVI, q);
            const int M = 1 << (9 - q);
            const float fr = (lane & M) ? vr : ur;
            const float fi = (lane & M) ? vi : ui;
            const float nr = Lr * fr - Li * fi;
            const float ni = Lr * fi + Li * fr;
            Lr = nr; Li = ni;
        }
        c[0] = (f2){Lr, Li};
#pragma unroll
        for (int r = 1; r < 16; ++r) c[r] = (f2){0.f, 0.f};
#pragma unroll
        for (int q = 3; q >= 0; --q) {
            const int m = 1 << (3 - q);
            const float ur = readlane_f(cUR, q), ui = readlane_f(cUI, q);
            const float vr = readlane_f(cVR, q), vi = readlane_f(cVI, q);
#pragma unroll
            for (int r0 = 0; r0 < 16; ++r0) {
                if (r0 >= m) continue;
                const f2 s = c[r0];
                c[r0 | m] = (f2){ s.x*vr - s.y*vi, s.x*vi + s.y*vr };
                c[r0]     = (f2){ s.x*ur - s.y*ui, s.x*ui + s.y*ur };
            }
        }
    }

#define SWAPR(i, j) { f2 _t = c[i]; c[i] = c[j]; c[j] = _t; }
#define SW01 SWAPR(8, 12) SWAPR(9, 13) SWAPR(10, 14) SWAPR(11, 15)
#define SW12 SWAPR(4, 6)  SWAPR(5, 7)  SWAPR(12, 14) SWAPR(13, 15)
#define SW23 SWAPR(2, 3)  SWAPR(6, 7)  SWAPR(10, 11) SWAPR(14, 15)
#define CONDSWAP90 { const bool ctl = (lane & 1) != 0;                        \
    _Pragma("unroll")                                                         \
    for (int r = 0; r < 8; ++r) {                                             \
        const f2 t0 = c[r], t1 = c[r + 8];                                    \
        c[r]     = ctl ? t1 : t0;                                             \
        c[r + 8] = ctl ? t0 : t1;                                             \
    } }
#define COEFF(Q) const float ur = readlane_f(cUR, base + (Q));                \
                 const float ui = readlane_f(cUI, base + (Q));                \
                 const float vr = readlane_f(cVR, base + (Q));                \
                 const float vi = readlane_f(cVI, base + (Q));
#define RG(Q)            { COEFF(Q) reg_gate<Q>(c, ur, ui, vr, vi); }
#define LG(Q, BQM, RF)   { COEFF(Q) lane_gate<(1 << (9 - (Q))), BQM, RF>(     \
                               c, lane, ur, ui, vr, vi, a16, a32); }

    // ===== ring 0 (explicit — layer 0 has no gates to fold into) =====
    {
        SW01 SW12 SW23
#pragma unroll
        for (int r = 0; r < 16; ++r) {
            const int addr = (r & 1) ? addr_odd : addr_even;
            c[r].x = bperm_f(addr, c[r].x);
            c[r].y = bperm_f(addr, c[r].y);
        }
        CONDSWAP90
    }

    // ===== layers 1..3: gates with folded ring edges =====
    for (int layer = 1; layer < NL - 1; ++layer) {
        const int base = layer * NQ;
        RG(0) RG(1) SW01 RG(2) SW12 RG(3) SW23
        LG(4, 0, true)        // carries C(3,4): ctrl r-bit0
        LG(5, 32, false)      // carries C(4,5): ctrl lane&32
        LG(6, 16, false)      // carries C(5,6): ctrl lane&16
        LG(7, 8,  false)      // carries C(6,7): ctrl lane&8
        LG(8, 4,  false)      // carries C(7,8): ctrl lane&4
        LG(9, 2,  false)      // carries C(8,9): ctrl lane&2
        CONDSWAP90            // C(9,0): ctrl lane&1, tgt r-bit3
    }

    // ===== layer 4: plain gates; ring 4 folded into epilogue parities =====
    {
        const int base = 4 * NQ;
        RG(0) RG(1) RG(2) RG(3)
        LG(4, 0, false) LG(5, 0, false) LG(6, 0, false)
        LG(7, 0, false) LG(8, 0, false) LG(9, 0, false)
    }

    // ---- epilogue: <Z_i> after the (virtual) final ring ----
    // (Cb)_0 = q1+..+q9 -> reg bits r2,r1,r0 + all 6 lane bits
    // (Cb)_1 = q0+q1 -> r3,r2 ; (Cb)_2 -> r3,r2,r1 ; (Cb)_3 -> r3..r0
    const float sL = (__popc(lane) & 1) ? -1.f : 1.f;
    float z0 = 0.f, z1 = 0.f, z2 = 0.f, z3 = 0.f;
#pragma unroll
    for (int r = 0; r < 16; ++r) {
        const float pv  = c[r].x * c[r].x + c[r].y * c[r].y;
        const float pvl = sL * pv;
        z0 += (__popc(r & 7)  & 1) ? -pvl : pvl;
        z1 += (__popc(r & 12) & 1) ? -pv  : pv;
        z2 += (__popc(r & 14) & 1) ? -pv  : pv;
        z3 += (__popc(r & 15) & 1) ? -pv  : pv;
    }
#pragma unroll
    for (int m = 1; m < 64; m <<= 1) {
        z0 += xor_lane(z0, m, a16, a32);
        z1 += xor_lane(z1, m, a16, a32);
        z2 += xor_lane(z2, m, a16, a32);
        z3 += xor_lane(z3, m, a16, a32);
    }
    if (lane == 0) {
        out[wid * 4 + 0] = z0 * oscale[0];
        out[wid * 4 + 1] = z1 * oscale[1];
        out[wid * 4 + 2] = z2 * oscale[2];
        out[wid * 4 + 3] = z3 * oscale[3];
    }
#undef SWAPR
#undef SW01
#undef SW12
#undef SW23
#undef CONDSWAP90
#undef COEFF
#undef RG
#undef LG
}

extern "C" void kernel_launch(void* const* d_in, const int* in_sizes, int n_in,
                              void* d_out, int out_size, void* d_ws, size_t ws_size,
                              hipStream_t stream) {
    const float* x      = (const float*)d_in[0];
    const float* isc    = (const float*)d_in[1];
    const float* w      = (const float*)d_in[2];
    const float* oscale = (const float*)d_in[3];
    float* out = (float*)d_out;

    const int B = in_sizes[0] / OBS;             // 4096
    const int threads = 256;                     // 4 waves -> 4 samples per block
    const int blocks = (B * 64 + threads - 1) / threads;
    qsim_kernel<<<blocks, threads, 0, stream>>>(x, isc, w, oscale, out, B);
}

// Round 14
// 91.860 us; speedup vs baseline: 1.0039x; 1.0039x over previous
//
#include <hip/hip_runtime.h>

// Batched 10-qubit statevector simulator — one 64-lane wave per sample.
// State: 1024 complex amps; s = (r<<6)|lane; qubit q <-> bit (9-q):
//   qubits 0..3 -> register-index bits (16 complex float2 per lane)
//   qubits 4..9 -> lane bits (butterfly exchanges)
// Per layer per qubit, RY(a)RZ(b)RZ(g)RY(d) fuse into one SU(2)
// U = [[u, -conj(v)],[v, conj(u)]], p=(b+g)/2.
// R1/R2: 50 gate coefficient sets lane-parallel, broadcast via v_readlane.
// R3: __launch_bounds__(256,4); CNOT chain (3,4)..(8,9) fused to one
//     ds_bpermute pass (dest lane d pulls s = (d^(d>>1)) ^ ((r&1)<<5)).
// R4: float2 state -> VOP3P v_pk_fma_f32.
// R5: masks 1,2 (quad_perm) and 8 (row_ror:8) via DPP on the VALU pipe.
// R9: layer-0 -> product-state construction; final ring -> epilogue parities.
// R10: mask-4 = 2-DPP chain (0x1B then 0x141). [best: 41.8 us]
// R11 (stagger) and R12 (ring folding) both NEUTRAL -> DS is NOT saturated
//     (~28% of elapsed); VALUBusy pinned at 61-63% across all variants
//     suggests a fixed front-end stall.
// R13: force the layer loop ROLLED (#pragma unroll 1). Fully unrolled, the
//     5-layer body is ~35-40 KB of straight-line code > 32 KB L1I -> every
//     wave streams it, thrashing the I-cache — a structure-independent ~37%
//     stall. Rolled body (~7 KB) fits L1I. Single-variable change vs R10.

constexpr int NQ  = 10;
constexpr int NL  = 5;
constexpr int OBS = 10;

typedef float f2 __attribute__((ext_vector_type(2)));

__device__ __forceinline__ float readlane_f(float v, int l) {
    return __int_as_float(__builtin_amdgcn_readlane(__float_as_int(v), l));
}
__device__ __forceinline__ float bperm_f(int byte_addr, float v) {
    return __int_as_float(__builtin_amdgcn_ds_bpermute(byte_addr, __float_as_int(v)));
}
template <int CTRL>
__device__ __forceinline__ float dpp_f(float v) {
    return __int_as_float(__builtin_amdgcn_update_dpp(
        0, __float_as_int(v), CTRL, 0xF, 0xF, true));
}
// xor-exchange across lanes; M compile-time -> branches fold.
__device__ __forceinline__ float xor_lane(float v, int M, int a16, int a32) {
    switch (M) {
    case 1:  return dpp_f<0xB1>(v);               // quad_perm [1,0,3,2]
    case 2:  return dpp_f<0x4E>(v);               // quad_perm [2,3,0,1]
    case 8:  return dpp_f<0x128>(v);              // row_ror:8 == lane^8
    case 4:  return dpp_f<0x141>(dpp_f<0x1B>(v)); // xor3 ∘ xor7 = xor4
    case 16: return bperm_f(a16, v);
    default: return bperm_f(a32, v);              // 32
    }
}

__global__ __launch_bounds__(256, 4) void qsim_kernel(
    const float* __restrict__ x,       // (B, 10)
    const float* __restrict__ isc,     // (5, 20)
    const float* __restrict__ w,       // (5, 20)
    const float* __restrict__ oscale,  // (4)
    float* __restrict__ out,           // (B, 4)
    int B)
{
    const int lane = threadIdx.x & 63;
    const int wid  = (blockIdx.x * blockDim.x + threadIdx.x) >> 6;
    if (wid >= B) return;

    // ---- lane-parallel gate-coefficient computation (gates 0..49) ----
    float cUR, cUI, cVR, cVI;
    {
        const int g   = (lane < 50) ? lane : 49;
        const int q   = g % 10;
        const int lyr = g / 10;
        const float xq    = x[wid * OBS + q];
        const float alpha = isc[lyr * 2 * NQ + q]      * xq;
        const float beta  = isc[lyr * 2 * NQ + NQ + q] * xq;
        const float gamma = w[lyr * 2 * NQ + q];
        const float delta = w[lyr * 2 * NQ + NQ + q];
        float sa, ca, sp, cp, sd, cd;
        __sincosf(0.5f * alpha,          &sa, &ca);
        __sincosf(0.5f * (beta + gamma), &sp, &cp);
        __sincosf(0.5f * delta,          &sd, &cd);
        const float A = cd * ca, Bt = sd * sa;
        const float C = cd * sa, D  = sd * ca;
        cUR = (A - Bt) * cp;
        cUI = -(A + Bt) * sp;
        cVR = (C + D) * cp;
        cVI = (C - D) * sp;
    }

    // hoisted bpermute byte-addresses (loop-invariant)
    const int a16 = (lane ^ 16) * 4;
    const int a32 = (lane ^ 32) * 4;
    const int cnot_src  = (lane ^ (lane >> 1));
    const int addr_even = cnot_src * 4;            // r bit0 == 0
    const int addr_odd  = (cnot_src ^ 32) * 4;     // r bit0 == 1 (CNOT(3,4))

    f2 c[16];

    // ===== layer 0: direct product-state construction =====
    // amp(s) = prod_q (bit_q(s) ? v_q : u_q), using gate column (u,v)=U|0>.
    {
        float Lr = 1.f, Li = 0.f;
#pragma unroll
        for (int q = 4; q < 10; ++q) {
            const float ur = readlane_f(cUR, q), ui = readlane_f(cUI, q);
            const float vr = readlane_f(cVR, q), vi = readlane_f(cVI, q);
            const int M = 1 << (9 - q);
            const float fr = (lane & M) ? vr : ur;
            const float fi = (lane & M) ? vi : ui;
            const float nr = Lr * fr - Li * fi;
            const float ni = Lr * fi + Li * fr;
            Lr = nr; Li = ni;
        }
        c[0] = (f2){Lr, Li};
#pragma unroll
        for (int r = 1; r < 16; ++r) c[r] = (f2){0.f, 0.f};
#pragma unroll
        for (int q = 3; q >= 0; --q) {
            const int m = 1 << (3 - q);
            const float ur = readlane_f(cUR, q), ui = readlane_f(cUI, q);
            const float vr = readlane_f(cVR, q), vi = readlane_f(cVI, q);
#pragma unroll
            for (int r0 = 0; r0 < 16; ++r0) {
                if (r0 >= m) continue;
                const f2 s = c[r0];
                c[r0 | m] = (f2){ s.x*vr - s.y*vi, s.x*vi + s.y*vr };
                c[r0]     = (f2){ s.x*ur - s.y*ui, s.x*ui + s.y*ur };
            }
        }
    }

#define SWAPR(i, j) { f2 _t = c[i]; c[i] = c[j]; c[j] = _t; }

    // R13: keep this loop ROLLED — full unroll blows past the 32 KB L1I.
#pragma unroll 1
    for (int layer = 0; layer < NL; ++layer) {
        const int base = layer * NQ;   // wave-uniform

        // ---- fused single-qubit unitaries (layer 0 done by construction) ----
        if (layer > 0) {
#pragma unroll
            for (int q = 0; q < NQ; ++q) {
                const float ur = readlane_f(cUR, base + q);
                const float ui = readlane_f(cUI, base + q);
                const float vr = readlane_f(cVR, base + q);
                const float vi = readlane_f(cVI, base + q);
                const f2 kUU  = {ur, ur};
                const f2 kUIm = {-ui, ui};
                const f2 kVVn = {-vr, -vr};
                const f2 kVV  = {vr, vr};
                const f2 kVIm = {-vi, vi};
                const f2 kUIp = {ui, -ui};

                if (q < 4) {
                    // register-bit qubit: pair stride m inside the lane.
                    const int m = 1 << (3 - q);
#pragma unroll
                    for (int r0 = 0; r0 < 16; ++r0) {
                        if (r0 & m) continue;
                        const int r1 = r0 | m;
                        const f2 c0 = c[r0], c1 = c[r1];
                        const f2 c0s = c0.yx, c1s = c1.yx;
                        c[r0] = kUU*c0 + kUIm*c0s + kVVn*c1 + kVIm*c1s;
                        c[r1] = kVV*c0 + kVIm*c0s + kUU*c1  + kUIp*c1s;
                    }
                } else {
                    // lane-bit qubit: butterfly exchange with lane^M.
                    const int  M   = 1 << (9 - q);
                    const bool bit = (lane & M) != 0;
                    const float Pi = bit ? -ui : ui;
                    const float Qr = bit ?  vr : -vr;
                    const f2 kUUb = {ur, ur};
                    const f2 kPI  = {-Pi, Pi};
                    const f2 kQR  = {Qr, Qr};
                    const f2 kVIb = {-vi, vi};
#pragma unroll
                    for (int r = 0; r < 16; ++r) {
                        const f2 mv = c[r];
                        f2 pv;
                        pv.x = xor_lane(mv.x, M, a16, a32);
                        pv.y = xor_lane(mv.y, M, a16, a32);
                        c[r] = kUUb*mv + kPI*mv.yx + kQR*pv + kVIb*pv.yx;
                    }
                }
            }
        }

        // ---- CNOT ring (skipped on last layer; folded into epilogue) ----
        if (layer < NL - 1) {
            // CNOT(0,1): ctrl r-bit3, tgt r-bit2 -> register swap
            SWAPR(8, 12) SWAPR(9, 13) SWAPR(10, 14) SWAPR(11, 15)
            // CNOT(1,2): ctrl r-bit2, tgt r-bit1
            SWAPR(4, 6)  SWAPR(5, 7)  SWAPR(12, 14) SWAPR(13, 15)
            // CNOT(2,3): ctrl r-bit1, tgt r-bit0
            SWAPR(2, 3)  SWAPR(6, 7)  SWAPR(10, 11) SWAPR(14, 15)
            // CNOT(3,4)..(8,9) fused: one bpermute per 32-bit value.
#pragma unroll
            for (int r = 0; r < 16; ++r) {
                const int addr = (r & 1) ? addr_odd : addr_even;
                c[r].x = bperm_f(addr, c[r].x);
                c[r].y = bperm_f(addr, c[r].y);
            }
            // CNOT(9,0): ctrl lane-bit0, tgt r-bit3 -> cond register swap
            const bool ctl = (lane & 1) != 0;
#pragma unroll
            for (int r = 0; r < 8; ++r) {
                const f2 t0 = c[r], t1 = c[r + 8];
                c[r]     = ctl ? t1 : t0;
                c[r + 8] = ctl ? t0 : t1;
            }
        }
    }

    // ---- epilogue: <Z_i> after the (virtual) final ring ----
    // (Cb)_0 = q1+..+q9 -> reg bits r2,r1,r0 + all 6 lane bits
    // (Cb)_1 = q0+q1 -> r3,r2 ; (Cb)_2 -> r3,r2,r1 ; (Cb)_3 -> r3..r0
    const float sL = (__popc(lane) & 1) ? -1.f : 1.f;
    float z0 = 0.f, z1 = 0.f, z2 = 0.f, z3 = 0.f;
#pragma unroll
    for (int r = 0; r < 16; ++r) {
        const float pv  = c[r].x * c[r].x + c[r].y * c[r].y;
        const float pvl = sL * pv;
        z0 += (__popc(r & 7)  & 1) ? -pvl : pvl;
        z1 += (__popc(r & 12) & 1) ? -pv  : pv;
        z2 += (__popc(r & 14) & 1) ? -pv  : pv;
        z3 += (__popc(r & 15) & 1) ? -pv  : pv;
    }
#pragma unroll
    for (int m = 1; m < 64; m <<= 1) {
        z0 += xor_lane(z0, m, a16, a32);
        z1 += xor_lane(z1, m, a16, a32);
        z2 += xor_lane(z2, m, a16, a32);
        z3 += xor_lane(z3, m, a16, a32);
    }
    if (lane == 0) {
        out[wid * 4 + 0] = z0 * oscale[0];
        out[wid * 4 + 1] = z1 * oscale[1];
        out[wid * 4 + 2] = z2 * oscale[2];
        out[wid * 4 + 3] = z3 * oscale[3];
    }
#undef SWAPR
}

extern "C" void kernel_launch(void* const* d_in, const int* in_sizes, int n_in,
                              void* d_out, int out_size, void* d_ws, size_t ws_size,
                              hipStream_t stream) {
    const float* x      = (const float*)d_in[0];
    const float* isc    = (const float*)d_in[1];
    const float* w      = (const float*)d_in[2];
    const float* oscale = (const float*)d_in[3];
    float* out = (float*)d_out;

    const int B = in_sizes[0] / OBS;             // 4096
    const int threads = 256;                     // 4 waves -> 4 samples per block
    const int blocks = (B * 64 + threads - 1) / threads;
    qsim_kernel<<<blocks, threads, 0, stream>>>(x, isc, w, oscale, out, B);
}

// Round 15
// 88.840 us; speedup vs baseline: 1.0380x; 1.0340x over previous
//
#include <hip/hip_runtime.h>

// Batched 10-qubit statevector simulator — one 64-lane wave per sample.
// State: 1024 complex amps; s = (r<<6)|lane; qubit q <-> bit (9-q):
//   qubits 0..3 -> register-index bits (16 regs per lane)
//   qubits 4..9 -> lane bits (butterfly exchanges)
// R14: state stored as PACKED FP16 complex — one f16x2 VGPR per amplitude.
//   v_pk_fma_f16 is FULL-rate (2cyc) vs v_pk_fma_f32 half-rate (4cyc), and
//   every cross-lane op (DPP/bperm/cndmask) now moves re+im in ONE 32-bit
//   op. Gate math, DS traffic, DPP movs, CNOT selects all ~halve.
//   Coefficients stay fp32 (sincos + readlane broadcast), converted to f16x2
//   per gate; layer-0 construction and epilogue accumulate in fp32.
//   Precision budget: ~sqrt(44 gates)*2^-11 rel -> <Z> err ~1e-3 < 3.59e-3.
// Carried: R1/2 lane-parallel coeffs + readlane; R3 fused ring chain bperm;
//   R5/R10 DPP masks 1,2,8 + 2-DPP mask 4; R9 layer-0 product construction
//   + final ring folded into epilogue parities. [R10 fp32 best: 41.8 us,
//   VALUBusy 62% — pure issue-count bound; R11/12/13 restructurings neutral]

constexpr int NQ  = 10;
constexpr int NL  = 5;
constexpr int OBS = 10;

typedef float    f2 __attribute__((ext_vector_type(2)));
typedef _Float16 h2 __attribute__((ext_vector_type(2)));

__device__ __forceinline__ float readlane_f(float v, int l) {
    return __int_as_float(__builtin_amdgcn_readlane(__float_as_int(v), l));
}
__device__ __forceinline__ int h2_to_i(h2 v) { int i; __builtin_memcpy(&i, &v, 4); return i; }
__device__ __forceinline__ h2  i_to_h2(int i) { h2 v; __builtin_memcpy(&v, &i, 4); return v; }

__device__ __forceinline__ h2 bperm_h2(int byte_addr, h2 v) {
    return i_to_h2(__builtin_amdgcn_ds_bpermute(byte_addr, h2_to_i(v)));
}
template <int CTRL>
__device__ __forceinline__ h2 dpp_h2(h2 v) {
    return i_to_h2(__builtin_amdgcn_update_dpp(0, h2_to_i(v), CTRL, 0xF, 0xF, true));
}
// xor-exchange across lanes; M compile-time -> branches fold.
__device__ __forceinline__ h2 xor_lane(h2 v, int M, int a16, int a32) {
    switch (M) {
    case 1:  return dpp_h2<0xB1>(v);               // quad_perm [1,0,3,2]
    case 2:  return dpp_h2<0x4E>(v);               // quad_perm [2,3,0,1]
    case 8:  return dpp_h2<0x128>(v);              // row_ror:8 == lane^8
    case 4:  return dpp_h2<0x141>(dpp_h2<0x1B>(v)); // xor3 ∘ xor7 = xor4
    case 16: return bperm_h2(a16, v);
    default: return bperm_h2(a32, v);              // 32
    }
}
__device__ __forceinline__ h2 mk_h2(float a, float b) {
    h2 r; r.x = (_Float16)a; r.y = (_Float16)b; return r;
}

__global__ __launch_bounds__(256, 4) void qsim_kernel(
    const float* __restrict__ x,       // (B, 10)
    const float* __restrict__ isc,     // (5, 20)
    const float* __restrict__ w,       // (5, 20)
    const float* __restrict__ oscale,  // (4)
    float* __restrict__ out,           // (B, 4)
    int B)
{
    const int lane = threadIdx.x & 63;
    const int wid  = (blockIdx.x * blockDim.x + threadIdx.x) >> 6;
    if (wid >= B) return;

    // ---- lane-parallel gate-coefficient computation (gates 0..49), fp32 ----
    float cUR, cUI, cVR, cVI;
    {
        const int g   = (lane < 50) ? lane : 49;
        const int q   = g % 10;
        const int lyr = g / 10;
        const float xq    = x[wid * OBS + q];
        const float alpha = isc[lyr * 2 * NQ + q]      * xq;
        const float beta  = isc[lyr * 2 * NQ + NQ + q] * xq;
        const float gamma = w[lyr * 2 * NQ + q];
        const float delta = w[lyr * 2 * NQ + NQ + q];
        float sa, ca, sp, cp, sd, cd;
        __sincosf(0.5f * alpha,          &sa, &ca);
        __sincosf(0.5f * (beta + gamma), &sp, &cp);
        __sincosf(0.5f * delta,          &sd, &cd);
        const float A = cd * ca, Bt = sd * sa;
        const float C = cd * sa, D  = sd * ca;
        cUR = (A - Bt) * cp;
        cUI = -(A + Bt) * sp;
        cVR = (C + D) * cp;
        cVI = (C - D) * sp;
    }

    // hoisted bpermute byte-addresses (loop-invariant)
    const int a16 = (lane ^ 16) * 4;
    const int a32 = (lane ^ 32) * 4;
    const int cnot_src  = (lane ^ (lane >> 1));
    const int addr_even = cnot_src * 4;            // r bit0 == 0
    const int addr_odd  = (cnot_src ^ 32) * 4;     // r bit0 == 1 (CNOT(3,4))

    h2 c[16];

    // ===== layer 0: direct product-state construction (fp32 -> f16x2) =====
    // amp(s) = prod_q (bit_q(s) ? v_q : u_q), gate column (u,v)=U|0>.
    {
        float Lr = 1.f, Li = 0.f;
#pragma unroll
        for (int q = 4; q < 10; ++q) {
            const float ur = readlane_f(cUR, q), ui = readlane_f(cUI, q);
            const float vr = readlane_f(cVR, q), vi = readlane_f(cVI, q);
            const int M = 1 << (9 - q);
            const float fr = (lane & M) ? vr : ur;
            const float fi = (lane & M) ? vi : ui;
            const float nr = Lr * fr - Li * fi;
            const float ni = Lr * fi + Li * fr;
            Lr = nr; Li = ni;
        }
        f2 cf[16];
        cf[0] = (f2){Lr, Li};
#pragma unroll
        for (int r = 1; r < 16; ++r) cf[r] = (f2){0.f, 0.f};
#pragma unroll
        for (int q = 3; q >= 0; --q) {
            const int m = 1 << (3 - q);
            const float ur = readlane_f(cUR, q), ui = readlane_f(cUI, q);
            const float vr = readlane_f(cVR, q), vi = readlane_f(cVI, q);
#pragma unroll
            for (int r0 = 0; r0 < 16; ++r0) {
                if (r0 >= m) continue;
                const f2 s = cf[r0];
                cf[r0 | m] = (f2){ s.x*vr - s.y*vi, s.x*vi + s.y*vr };
                cf[r0]     = (f2){ s.x*ur - s.y*ui, s.x*ui + s.y*ur };
            }
        }
#pragma unroll
        for (int r = 0; r < 16; ++r) c[r] = mk_h2(cf[r].x, cf[r].y);
    }

#define SWAPR(i, j) { h2 _t = c[i]; c[i] = c[j]; c[j] = _t; }

    for (int layer = 0; layer < NL; ++layer) {
        const int base = layer * NQ;   // wave-uniform

        // ---- fused single-qubit unitaries (layer 0 done by construction) ----
        if (layer > 0) {
#pragma unroll
            for (int q = 0; q < NQ; ++q) {
                const float ur = readlane_f(cUR, base + q);
                const float ui = readlane_f(cUI, base + q);
                const float vr = readlane_f(cVR, base + q);
                const float vi = readlane_f(cVI, base + q);

                if (q < 4) {
                    // register-bit qubit: pair stride m inside the lane.
                    const h2 kUU  = mk_h2(ur, ur);
                    const h2 kUIm = mk_h2(-ui, ui);
                    const h2 kVVn = mk_h2(-vr, -vr);
                    const h2 kVV  = mk_h2(vr, vr);
                    const h2 kVIm = mk_h2(-vi, vi);
                    const h2 kUIp = mk_h2(ui, -ui);
                    const int m = 1 << (3 - q);
#pragma unroll
                    for (int r0 = 0; r0 < 16; ++r0) {
                        if (r0 & m) continue;
                        const int r1 = r0 | m;
                        const h2 c0 = c[r0], c1 = c[r1];
                        const h2 c0s = c0.yx, c1s = c1.yx;
                        c[r0] = kUU*c0 + kUIm*c0s + kVVn*c1 + kVIm*c1s;
                        c[r1] = kVV*c0 + kVIm*c0s + kUU*c1  + kUIp*c1s;
                    }
                } else {
                    // lane-bit qubit: butterfly exchange with lane^M.
                    const int  M   = 1 << (9 - q);
                    const bool bit = (lane & M) != 0;
                    const float Pi = bit ? -ui : ui;
                    const float Qr = bit ?  vr : -vr;
                    const h2 kUUb = mk_h2(ur, ur);
                    const h2 kPI  = mk_h2(-Pi, Pi);
                    const h2 kQR  = mk_h2(Qr, Qr);
                    const h2 kVIb = mk_h2(-vi, vi);
#pragma unroll
                    for (int r = 0; r < 16; ++r) {
                        const h2 mv = c[r];
                        const h2 pv = xor_lane(mv, M, a16, a32);
                        c[r] = kUUb*mv + kPI*mv.yx + kQR*pv + kVIb*pv.yx;
                    }
                }
            }
        }

        // ---- CNOT ring (skipped on last layer; folded into epilogue) ----
        if (layer < NL - 1) {
            // CNOT(0,1): ctrl r-bit3, tgt r-bit2 -> register swap
            SWAPR(8, 12) SWAPR(9, 13) SWAPR(10, 14) SWAPR(11, 15)
            // CNOT(1,2): ctrl r-bit2, tgt r-bit1
            SWAPR(4, 6)  SWAPR(5, 7)  SWAPR(12, 14) SWAPR(13, 15)
            // CNOT(2,3): ctrl r-bit1, tgt r-bit0
            SWAPR(2, 3)  SWAPR(6, 7)  SWAPR(10, 11) SWAPR(14, 15)
            // CNOT(3,4)..(8,9) fused: ONE bpermute per amplitude (f16x2).
#pragma unroll
            for (int r = 0; r < 16; ++r) {
                const int addr = (r & 1) ? addr_odd : addr_even;
                c[r] = bperm_h2(addr, c[r]);
            }
            // CNOT(9,0): ctrl lane-bit0, tgt r-bit3 -> cond register swap
            const bool ctl = (lane & 1) != 0;
#pragma unroll
            for (int r = 0; r < 8; ++r) {
                const h2 t0 = c[r], t1 = c[r + 8];
                c[r]     = ctl ? t1 : t0;
                c[r + 8] = ctl ? t0 : t1;
            }
        }
    }

    // ---- epilogue (fp32): <Z_i> after the (virtual) final ring ----
    // (Cb)_0 = q1+..+q9 -> reg bits r2,r1,r0 + all 6 lane bits
    // (Cb)_1 = q0+q1 -> r3,r2 ; (Cb)_2 -> r3,r2,r1 ; (Cb)_3 -> r3..r0
    const float sL = (__popc(lane) & 1) ? -1.f : 1.f;
    float z0 = 0.f, z1 = 0.f, z2 = 0.f, z3 = 0.f;
#pragma unroll
    for (int r = 0; r < 16; ++r) {
        const float cr = (float)c[r].x, ci = (float)c[r].y;
        const float pv  = cr * cr + ci * ci;
        const float pvl = sL * pv;
        z0 += (__popc(r & 7)  & 1) ? -pvl : pvl;
        z1 += (__popc(r & 12) & 1) ? -pv  : pv;
        z2 += (__popc(r & 14) & 1) ? -pv  : pv;
        z3 += (__popc(r & 15) & 1) ? -pv  : pv;
    }
    // f32 xor-lane reduction (DPP for 1,2,4,8; bperm for 16,32)
#pragma unroll
    for (int m = 1; m < 64; m <<= 1) {
        if (m == 1)      { z0 += __int_as_float(__builtin_amdgcn_update_dpp(0, __float_as_int(z0), 0xB1, 0xF, 0xF, true));
                           z1 += __int_as_float(__builtin_amdgcn_update_dpp(0, __float_as_int(z1), 0xB1, 0xF, 0xF, true));
                           z2 += __int_as_float(__builtin_amdgcn_update_dpp(0, __float_as_int(z2), 0xB1, 0xF, 0xF, true));
                           z3 += __int_as_float(__builtin_amdgcn_update_dpp(0, __float_as_int(z3), 0xB1, 0xF, 0xF, true)); }
        else if (m == 2) { z0 += __int_as_float(__builtin_amdgcn_update_dpp(0, __float_as_int(z0), 0x4E, 0xF, 0xF, true));
                           z1 += __int_as_float(__builtin_amdgcn_update_dpp(0, __float_as_int(z1), 0x4E, 0xF, 0xF, true));
                           z2 += __int_as_float(__builtin_amdgcn_update_dpp(0, __float_as_int(z2), 0x4E, 0xF, 0xF, true));
                           z3 += __int_as_float(__builtin_amdgcn_update_dpp(0, __float_as_int(z3), 0x4E, 0xF, 0xF, true)); }
        else if (m == 4) { z0 += __int_as_float(__builtin_amdgcn_update_dpp(0, __builtin_amdgcn_update_dpp(0, __float_as_int(z0), 0x1B, 0xF, 0xF, true), 0x141, 0xF, 0xF, true));
                           z1 += __int_as_float(__builtin_amdgcn_update_dpp(0, __builtin_amdgcn_update_dpp(0, __float_as_int(z1), 0x1B, 0xF, 0xF, true), 0x141, 0xF, 0xF, true));
                           z2 += __int_as_float(__builtin_amdgcn_update_dpp(0, __builtin_amdgcn_update_dpp(0, __float_as_int(z2), 0x1B, 0xF, 0xF, true), 0x141, 0xF, 0xF, true));
                           z3 += __int_as_float(__builtin_amdgcn_update_dpp(0, __builtin_amdgcn_update_dpp(0, __float_as_int(z3), 0x1B, 0xF, 0xF, true), 0x141, 0xF, 0xF, true)); }
        else if (m == 8) { z0 += __int_as_float(__builtin_amdgcn_update_dpp(0, __float_as_int(z0), 0x128, 0xF, 0xF, true));
                           z1 += __int_as_float(__builtin_amdgcn_update_dpp(0, __float_as_int(z1), 0x128, 0xF, 0xF, true));
                           z2 += __int_as_float(__builtin_amdgcn_update_dpp(0, __float_as_int(z2), 0x128, 0xF, 0xF, true));
                           z3 += __int_as_float(__builtin_amdgcn_update_dpp(0, __float_as_int(z3), 0x128, 0xF, 0xF, true)); }
        else if (m == 16){ z0 += __int_as_float(__builtin_amdgcn_ds_bpermute(a16, __float_as_int(z0)));
                           z1 += __int_as_float(__builtin_amdgcn_ds_bpermute(a16, __float_as_int(z1)));
                           z2 += __int_as_float(__builtin_amdgcn_ds_bpermute(a16, __float_as_int(z2)));
                           z3 += __int_as_float(__builtin_amdgcn_ds_bpermute(a16, __float_as_int(z3))); }
        else             { z0 += __int_as_float(__builtin_amdgcn_ds_bpermute(a32, __float_as_int(z0)));
                           z1 += __int_as_float(__builtin_amdgcn_ds_bpermute(a32, __float_as_int(z1)));
                           z2 += __int_as_float(__builtin_amdgcn_ds_bpermute(a32, __float_as_int(z2)));
                           z3 += __int_as_float(__builtin_amdgcn_ds_bpermute(a32, __float_as_int(z3))); }
    }
    if (lane == 0) {
        out[wid * 4 + 0] = z0 * oscale[0];
        out[wid * 4 + 1] = z1 * oscale[1];
        out[wid * 4 + 2] = z2 * oscale[2];
        out[wid * 4 + 3] = z3 * oscale[3];
    }
#undef SWAPR
}

extern "C" void kernel_launch(void* const* d_in, const int* in_sizes, int n_in,
                              void* d_out, int out_size, void* d_ws, size_t ws_size,
                              hipStream_t stream) {
    const float* x      = (const float*)d_in[0];
    const float* isc    = (const float*)d_in[1];
    const float* w      = (const float*)d_in[2];
    const float* oscale = (const float*)d_in[3];
    float* out = (float*)d_out;

    const int B = in_sizes[0] / OBS;             // 4096
    const int threads = 256;                     // 4 waves -> 4 samples per block
    const int blocks = (B * 64 + threads - 1) / threads;
    qsim_kernel<<<blocks, threads, 0, stream>>>(x, isc, w, oscale, out, B);
}